// Round 14
// baseline (645.138 us; speedup 1.0000x reference)
//
#include <hip/hip_runtime.h>

typedef unsigned short u16;
typedef unsigned int   u32;
typedef __attribute__((ext_vector_type(8))) short short8;
typedef __attribute__((ext_vector_type(4))) float float4v;
typedef __attribute__((ext_vector_type(2))) float float2v;

#define NODE_D   38
#define EDGE_D   13
#define D_OUT    128
#define NEG_SLOPE 0.2f
#define LN_EPS   1e-5f

__device__ __forceinline__ float bf2f(u16 v) { return __uint_as_float(((u32)v) << 16); }
__device__ __forceinline__ u16 f2bf(float f) {
    u32 u = __float_as_uint(f);
    u += 0x7fffu + ((u >> 16) & 1u);   // round-to-nearest-even
    return (u16)(u >> 16);
}

// ---------------- fused degree + graph-size count ----------------
__global__ void k_cnt(const int* __restrict__ dst, int E, int* __restrict__ deg,
                      const int* __restrict__ batch, int N, int* __restrict__ gcnt) {
    int i = blockIdx.x * blockDim.x + threadIdx.x;
    if (i < E) atomicAdd(deg + dst[i], 1);
    if (i < N) atomicAdd(gcnt + batch[i], 1);
}

// ---------------- multi-block exclusive scan (chunk = 1024), adds `addone` per elem ----------------
#define SCAN_CHUNK 1024
__global__ void k_scan1(const int* __restrict__ cnt, int N, int addone, int* __restrict__ bsum) {
    __shared__ int sh[256];
    int base = blockIdx.x * SCAN_CHUNK;
    int t = threadIdx.x;
    int s = 0;
#pragma unroll
    for (int i = 0; i < 4; i++) { int idx = base + t * 4 + i; if (idx < N) s += cnt[idx] + addone; }
    sh[t] = s; __syncthreads();
    for (int ofs = 128; ofs > 0; ofs >>= 1) {
        if (t < ofs) sh[t] += sh[t + ofs];
        __syncthreads();
    }
    if (t == 0) bsum[blockIdx.x] = sh[0];
}
// parallel block-sum scan (nb <= 256 fast path; serial fallback)
__global__ void k_scan2(const int* __restrict__ bsum, int nb, int* __restrict__ boff) {
    __shared__ int sh[256];
    int t = threadIdx.x;
    if (nb <= 256) {
        int v = (t < nb) ? bsum[t] : 0;
        sh[t] = v; __syncthreads();
        for (int ofs = 1; ofs < 256; ofs <<= 1) {
            int x = (t >= ofs) ? sh[t - ofs] : 0;
            __syncthreads();
            sh[t] += x;
            __syncthreads();
        }
        if (t < nb) boff[t] = sh[t] - v;       // exclusive
        if (t == nb - 1) boff[nb] = sh[t];     // total
    } else if (t == 0) {
        int run = 0;
        for (int i = 0; i < nb; i++) { boff[i] = run; run += bsum[i]; }
        boff[nb] = run;
    }
}
__global__ void k_scan3(const int* __restrict__ cnt, int N, int addone,
                        const int* __restrict__ boff, int nb, int* __restrict__ off) {
    __shared__ int wtot[4];
    int base = blockIdx.x * SCAN_CHUNK;
    int t = threadIdx.x;
    int lane = t & 63, w = t >> 6;
    int v[4]; int s = 0;
#pragma unroll
    for (int i = 0; i < 4; i++) { int idx = base + t * 4 + i; v[i] = (idx < N) ? cnt[idx] + addone : 0; s += v[i]; }
    int inc = s;
#pragma unroll
    for (int ofs = 1; ofs < 64; ofs <<= 1) {
        int x = __shfl_up(inc, ofs, 64);
        if (lane >= ofs) inc += x;
    }
    if (lane == 63) wtot[w] = inc;
    __syncthreads();
    int wofs = 0;
    for (int i = 0; i < w; i++) wofs += wtot[i];
    int run = boff[blockIdx.x] + wofs + (inc - s);
#pragma unroll
    for (int i = 0; i < 4; i++) {
        int idx = base + t * 4 + i;
        if (idx < N) off[idx] = run;
        run += v[i];
    }
    if (blockIdx.x == 0 && t == 0) off[N] = boff[nb];
}

// ---------------- CSR fill: scatter src AND the bf16 A-row (16-wide, padded) ----------------
__global__ void k_fill(const int* __restrict__ src, const int* __restrict__ dst,
                       const float* __restrict__ eattr, int E,
                       const int* __restrict__ csr_off, int* __restrict__ fill,
                       int* __restrict__ csr_src, u16* __restrict__ A) {
    int e = blockIdx.x * blockDim.x + threadIdx.x;
    if (e >= E) return;
    int d = dst[e];
    int pos = csr_off[d] + atomicAdd(fill + d, 1);
    csr_src[pos] = src[e];
    u16 row[16];
#pragma unroll
    for (int k = 0; k < EDGE_D; k++) row[k] = f2bf(eattr[(size_t)e * EDGE_D + k]);
#pragma unroll
    for (int k = EDGE_D; k < 16; k++) row[k] = 0;
    uint4* rp = (uint4*)(A + (size_t)pos * 16);
    rp[0] = (uint4){(u32)row[0] | ((u32)row[1] << 16), (u32)row[2] | ((u32)row[3] << 16),
                    (u32)row[4] | ((u32)row[5] << 16), (u32)row[6] | ((u32)row[7] << 16)};
    rp[1] = (uint4){(u32)row[8] | ((u32)row[9] << 16), (u32)row[10] | ((u32)row[11] << 16),
                    (u32)row[12] | ((u32)row[13] << 16), (u32)row[14] | ((u32)row[15] << 16)};
}

// ---------------- self rows: mean of node's (contiguous) real A rows; also self csr_src ----------------
__global__ void k_self(const int* __restrict__ csr_off, int N,
                       int* __restrict__ csr_src, u16* __restrict__ A) {
    int tid = blockIdx.x * blockDim.x + threadIdx.x;
    if (tid >= N * 16) return;
    int n = tid >> 4, k = tid & 15;
    int b = csr_off[n], e2 = csr_off[n + 1] - 1;   // e2 = self slot
    u16 v = 0;
    if (k < EDGE_D) {
        float s = 0.f;
        for (int j = b; j < e2; j++) s += bf2f(A[(size_t)j * 16 + k]);
        v = f2bf(s / fmaxf((float)(e2 - b), 1.f));
    }
    A[(size_t)e2 * 16 + k] = v;
    if (k == 0) csr_src[e2] = n;
}

// ---------------- MFMA multi-output transform ----------------
template <int KPAD, int CT, int KREAL, bool IN_BF16>
__global__ __launch_bounds__(256) void k_tf_mfma(
    const void* __restrict__ in_v,
    const float* __restrict__ W0, const float* __restrict__ b0,
    const float* __restrict__ W1, const float* __restrict__ b1,
    const float* __restrict__ W2, const float* __restrict__ b2,
    u16* __restrict__ o0, u16* __restrict__ o1, u16* __restrict__ o2,
    int N) {
    constexpr int RS = KPAD + 8;
    __shared__ u16 Bsw[CT * 16 * RS];
    __shared__ float bsh[CT * 16];
    const float* Ws[3] = {W0, W1, W2};
    const float* bs[3] = {b0, b1, b2};
    u16* outs[3] = {o0, o1, o2};
    int t = threadIdx.x;
    for (int i = t; i < CT * 16 * KPAD; i += 256) {
        int c = i / KPAD, k = i - c * KPAD;
        float v = (k < KREAL) ? Ws[c >> 7][(size_t)k * 128 + (c & 127)] : 0.f;
        Bsw[c * RS + k] = f2bf(v);
    }
    for (int i = t; i < CT * 16; i += 256) bsh[i] = bs[i >> 7][i & 127];
    __syncthreads();

    int wid = t >> 6, lane = t & 63;
    int quad = lane >> 4, m = lane & 15;

    for (int g0 = blockIdx.x * 64; g0 < N; g0 += gridDim.x * 64) {
        int na = g0 + wid * 16 + m;
        if (na > N - 1) na = N - 1;
        short8 a[KPAD / 32];
        if (IN_BF16) {
            const u16* in = (const u16*)in_v;
#pragma unroll
            for (int kc = 0; kc < KPAD / 32; kc++)
                a[kc] = *(const short8*)(in + (size_t)na * KPAD + kc * 32 + quad * 8);
        } else {
            const float* in = (const float*)in_v;
#pragma unroll
            for (int kc = 0; kc < KPAD / 32; kc++)
#pragma unroll
                for (int j = 0; j < 8; j++) {
                    int k = kc * 32 + quad * 8 + j;
                    float v = (k < KREAL) ? in[(size_t)na * KREAL + k] : 0.f;
                    a[kc][j] = (short)f2bf(v);
                }
        }
        float4v acc[CT];
#pragma unroll
        for (int ct = 0; ct < CT; ct++) acc[ct] = (float4v){0.f, 0.f, 0.f, 0.f};
#pragma unroll
        for (int ct = 0; ct < CT; ct++) {
#pragma unroll
            for (int kc = 0; kc < KPAD / 32; kc++) {
                short8 b = *(const short8*)(&Bsw[(ct * 16 + m) * RS + kc * 32 + quad * 8]);
                acc[ct] = __builtin_amdgcn_mfma_f32_16x16x32_bf16(a[kc], b, acc[ct], 0, 0, 0);
            }
        }
#pragma unroll
        for (int ct = 0; ct < CT; ct++) {
            int col = ct * 16 + m;
            u16* op = outs[col >> 7];
            int cc = col & 127;
            float bv = bsh[col];
#pragma unroll
            for (int r = 0; r < 4; r++) {
                int node = g0 + wid * 16 + quad * 4 + r;
                if (node < N) op[(size_t)node * 128 + cc] = f2bf(acc[ct][r] + bv);
            }
        }
    }
}

// ---------------- fused GATv2 block: flat edge loop + 2-slot named pipeline ----------------
// Each wave owns a contiguous node run => contiguous CSR edge range. Flat loop over
// edges with wave-uniform node-finalize check; two statically-named prefetch slots
// (A/B) keep ~4 loads in flight. No-max softmax (logits O(1)). Packed f32 math.
__global__ __launch_bounds__(256) void k_gat(
    const int* __restrict__ csr_off, const int* __restrict__ csr_src,
    const u16* __restrict__ A_csr,
    const u16* __restrict__ xl, const u16* __restrict__ xr,
    const u16* __restrict__ res, const float* __restrict__ We,
    const float* __restrict__ att, const float* __restrict__ ab,
    const float* __restrict__ lng, const float* __restrict__ lnb,
    u16* __restrict__ hout, int N, int npw) {
    int t = threadIdx.x;
    int wid = t >> 6, lane = t & 63;
    int wave = blockIdx.x * 4 + wid;
    int n0 = wave * npw;
    if (n0 >= N) return;
    int n1 = n0 + npw; if (n1 > N) n1 = N;

    // ---- node-invariant preamble (once per wave) ----
    float2v we2[EDGE_D];
#pragma unroll
    for (int k = 0; k < EDGE_D; k++)
        we2[k] = (float2v){We[k * D_OUT + 2 * lane], We[k * D_OUT + 2 * lane + 1]};
    float a0 = att[2 * lane], a1 = att[2 * lane + 1];
    float abv0 = ab[2 * lane], abv1 = ab[2 * lane + 1];
    float lg0 = lng[2 * lane], lg1 = lng[2 * lane + 1];
    float lb0 = lnb[2 * lane], lb1 = lnb[2 * lane + 1];

    const u32* xl32 = (const u32*)xl;
    int wbeg = csr_off[n0];
    int wend = csr_off[n1];
    int cl = wend - 1;

    // ---- two named prefetch slots (positions wbeg+even -> A, wbeg+odd -> B) ----
    u32 xwA = xl32[(size_t)csr_src[wbeg] * 64 + lane];
    const uint4* apA = (const uint4*)(A_csr + (size_t)wbeg * 16);
    uint4 aA0 = apA[0], aA1 = apA[1];
    int ib0 = (wbeg + 1 < wend) ? wbeg + 1 : cl;
    u32 xwB = xl32[(size_t)csr_src[ib0] * 64 + lane];
    const uint4* apB = (const uint4*)(A_csr + (size_t)ib0 * 16);
    uint4 aB0 = apB[0], aB1 = apB[1];

    // ---- per-node state ----
    int n = n0;
    int end = csr_off[n + 1];
    u32 xrw = ((const u32*)xr)[(size_t)n * 64 + lane];
    float2v xr2 = (float2v){bf2f((u16)(xrw & 0xffff)), bf2f((u16)(xrw >> 16))};
    float ssum = 0.f;
    float2v acc2 = (float2v){0.f, 0.f};
    int i = wbeg;

    auto edge = [&](u32 xwc, uint4 q0, uint4 q1) {
        u32 dw[8] = {q0.x, q0.y, q0.z, q0.w, q1.x, q1.y, q1.z, q1.w};
        float2v ee = (float2v){0.f, 0.f};
#pragma unroll
        for (int k = 0; k < EDGE_D; k++) {
            u32 d = dw[k >> 1];
            float av = bf2f((u16)((k & 1) ? (d >> 16) : (d & 0xffff)));
            ee += we2[k] * av;                      // v_pk_fma_f32
        }
        float2v xs = (float2v){bf2f((u16)(xwc & 0xffff)), bf2f((u16)(xwc >> 16))};
        float2v z = xs + xr2 + ee;
        float z0 = z[0], z1 = z[1];
        z0 = (z0 > 0.f) ? z0 : z0 * NEG_SLOPE;
        z1 = (z1 > 0.f) ? z1 : z1 * NEG_SLOPE;
        float p = z0 * a0 + z1 * a1;
        p += __shfl_xor(p, 1, 64);
        p += __shfl_xor(p, 2, 64);
        p += __shfl_xor(p, 4, 64);
        p += __shfl_xor(p, 8, 64);
        float wgt = __expf(p);          // no max-subtraction: logits are O(1)
        ssum += wgt;
        acc2 += xs * wgt;
    };
    auto finalize = [&]() {
        float inv = 1.f / ssum;
        float o0 = acc2[0] * inv + abv0;
        float o1 = acc2[1] * inv + abv1;
        o0 = (o0 > 0.f) ? o0 : (__expf(o0) - 1.f);   // ELU
        o1 = (o1 > 0.f) ? o1 : (__expf(o1) - 1.f);
        u32 rw = ((const u32*)res)[(size_t)n * 64 + lane];
        o0 += bf2f((u16)(rw & 0xffff));
        o1 += bf2f((u16)(rw >> 16));
        float sm = o0 + o1;
#pragma unroll
        for (int mk = 1; mk < 64; mk <<= 1) sm += __shfl_xor(sm, mk, 64);
        float mu = sm * (1.f / 128.f);
        float d0 = o0 - mu, d1 = o1 - mu;
        float vv = d0 * d0 + d1 * d1;
#pragma unroll
        for (int mk = 1; mk < 64; mk <<= 1) vv += __shfl_xor(vv, mk, 64);
        float rs = rsqrtf(vv * (1.f / 128.f) + LN_EPS);
        float h0 = d0 * rs * lg0 + lb0;
        float h1 = d1 * rs * lg1 + lb1;
        ((u32*)hout)[(size_t)n * 64 + lane] = (u32)f2bf(h0) | ((u32)f2bf(h1) << 16);
    };
    auto next_node = [&]() -> bool {   // returns false when wave is done
        n++;
        if (n >= n1) return false;
        end = csr_off[n + 1];
        u32 xw2 = ((const u32*)xr)[(size_t)n * 64 + lane];
        xr2 = (float2v){bf2f((u16)(xw2 & 0xffff)), bf2f((u16)(xw2 >> 16))};
        ssum = 0.f;
        acc2 = (float2v){0.f, 0.f};
        return true;
    };

    for (;;) {
        // ---- slot A (even position) ----
        edge(xwA, aA0, aA1);
        {
            int ip = (i + 2 < wend) ? i + 2 : cl;
            xwA = xl32[(size_t)csr_src[ip] * 64 + lane];
            const uint4* ap = (const uint4*)(A_csr + (size_t)ip * 16);
            aA0 = ap[0]; aA1 = ap[1];
        }
        if (i + 1 == end) {
            finalize();
            if (!next_node()) break;
        }
        i++;
        if (i >= wend) break;   // safety (unreachable: last node finalizes above)
        // ---- slot B (odd position) ----
        edge(xwB, aB0, aB1);
        {
            int ip = (i + 2 < wend) ? i + 2 : cl;
            xwB = xl32[(size_t)csr_src[ip] * 64 + lane];
            const uint4* ap = (const uint4*)(A_csr + (size_t)ip * 16);
            aB0 = ap[0]; aB1 = ap[1];
        }
        if (i + 1 == end) {
            finalize();
            if (!next_node()) break;
        }
        i++;
    }
}

// ---------------- fused mean-pool + readout MLP: one block (2 waves) per graph ----------------
__global__ __launch_bounds__(128) void k_pool_read(
    const u16* __restrict__ h2, const int* __restrict__ goff,
    const float* __restrict__ Wd1, const float* __restrict__ bd1,
    const float* __restrict__ Wd2, const float* __restrict__ bd2,
    float* __restrict__ out, int G) {
    __shared__ float psh[128];
    __shared__ float rsh[2][64];
    int g = blockIdx.x;
    int c = threadIdx.x;
    int b = goff[g], e = goff[g + 1];
    float s = 0.f;
    for (int n = b; n < e; n++) s += bf2f(h2[(size_t)n * 128 + c]);
    psh[c] = s / fmaxf((float)(e - b), 1.f);
    __syncthreads();
    int j = c & 63, hw = c >> 6;
    float acc = (hw == 0) ? bd1[j] : 0.f;
    int k0 = hw * 64;
    for (int k = k0; k < k0 + 64; k++)
        acc += psh[k] * Wd1[k * 64 + j];
    rsh[hw][j] = acc;
    __syncthreads();
    if (c < 64) {
        float a = fmaxf(rsh[0][c] + rsh[1][c], 0.f);
        float v = a * Wd2[c];
#pragma unroll
        for (int mk = 1; mk < 64; mk <<= 1) v += __shfl_xor(v, mk, 64);
        if (c == 0) out[g] = v + bd2[0];
    }
}

extern "C" void kernel_launch(void* const* d_in, const int* in_sizes, int n_in,
                              void* d_out, int out_size, void* d_ws, size_t ws_size,
                              hipStream_t stream) {
    const float* x     = (const float*)d_in[0];
    const int*   eidx  = (const int*)d_in[1];
    const float* eattr = (const float*)d_in[2];
    const int*   batch = (const int*)d_in[3];
    const float* Wl1 = (const float*)d_in[4],  *bl1 = (const float*)d_in[5];
    const float* Wr1 = (const float*)d_in[6],  *br1 = (const float*)d_in[7];
    const float* We1 = (const float*)d_in[8],  *att1 = (const float*)d_in[9],  *ab1 = (const float*)d_in[10];
    const float* lng1 = (const float*)d_in[11], *lnb1 = (const float*)d_in[12];
    const float* Wres = (const float*)d_in[13], *bres = (const float*)d_in[14];
    const float* Wl2 = (const float*)d_in[15], *bl2 = (const float*)d_in[16];
    const float* Wr2 = (const float*)d_in[17], *br2 = (const float*)d_in[18];
    const float* We2 = (const float*)d_in[19], *att2 = (const float*)d_in[20], *ab2 = (const float*)d_in[21];
    const float* lng2 = (const float*)d_in[22], *lnb2 = (const float*)d_in[23];
    const float* Wd1 = (const float*)d_in[24], *bd1 = (const float*)d_in[25];
    const float* Wd2 = (const float*)d_in[26], *bd2 = (const float*)d_in[27];

    int N = in_sizes[0] / NODE_D;
    int E = in_sizes[1] / 2;
    int G = out_size;
    int EN = E + N;
    const int* src = eidx;
    const int* dst = eidx + E;

    char* w = (char*)d_ws;
    auto alloc = [&](size_t bytes) -> char* {
        char* p = w;
        w += (bytes + 255) & ~(size_t)255;
        return p;
    };
    int NB  = (N + SCAN_CHUNK - 1) / SCAN_CHUNK;
    int NBG = (G + SCAN_CHUNK - 1) / SCAN_CHUNK;
    // ---- persistent buffers ----
    int*   csr_off  = (int*)alloc((size_t)(N + 1) * 4);
    int*   csr_src  = (int*)alloc((size_t)EN * 4);
    u16*   A_csr    = (u16*)alloc((size_t)(EN + 64) * 16 * 2);
    u16*   xlb      = (u16*)alloc((size_t)N * D_OUT * 2);
    u16*   xrb      = (u16*)alloc((size_t)N * D_OUT * 2);
    u16*   resb     = (u16*)alloc((size_t)N * D_OUT * 2);  // res1, then h2 output
    u16*   hb       = (u16*)alloc((size_t)N * D_OUT * 2);
    int*   gcnt     = (int*)alloc((size_t)G * 4);
    int*   gbsum    = (int*)alloc((size_t)NBG * 4);
    int*   gboff    = (int*)alloc((size_t)(NBG + 1) * 4);
    int*   goff     = (int*)alloc((size_t)(G + 1) * 4);
    // ---- scratch ----
    int*   deg      = (int*)alloc((size_t)N * 4);
    int*   fill     = (int*)alloc((size_t)N * 4);
    int*   bsum     = (int*)alloc((size_t)(NB + 1) * 4);
    int*   boff     = (int*)alloc((size_t)(NB + 1) * 4);

    hipMemsetAsync(deg, 0, (size_t)N * 4, stream);
    hipMemsetAsync(fill, 0, (size_t)N * 4, stream);
    hipMemsetAsync(gcnt, 0, (size_t)G * 4, stream);

    // ---- counts (fused) ----
    int mx = (E > N) ? E : N;
    k_cnt<<<(mx + 255) / 256, 256, 0, stream>>>(dst, E, deg, batch, N, gcnt);

    // ---- CSR with self-loops folded in; A rows written at scatter time ----
    k_scan1<<<NB, 256, 0, stream>>>(deg, N, 1, bsum);
    k_scan2<<<1, 256, 0, stream>>>(bsum, NB, boff);
    k_scan3<<<NB, 256, 0, stream>>>(deg, N, 1, boff, NB, csr_off);
    k_fill<<<(E + 255) / 256, 256, 0, stream>>>(src, dst, eattr, E, csr_off, fill, csr_src, A_csr);
    k_self<<<((size_t)N * 16 + 255) / 256, 256, 0, stream>>>(csr_off, N, csr_src, A_csr);

    // ---- graph offsets (batch sorted) ----
    k_scan1<<<NBG, 256, 0, stream>>>(gcnt, G, 0, gbsum);
    k_scan2<<<1, 256, 0, stream>>>(gbsum, NBG, gboff);
    k_scan3<<<NBG, 256, 0, stream>>>(gcnt, G, 0, gboff, NBG, goff);

    // ---- k_gat launch geometry: npw=4 -> 25000 waves ----
    int npw = 4;
    int gblocks = (N + npw * 4 - 1) / (npw * 4);

    // ---- block 1 ----
    k_tf_mfma<64, 24, NODE_D, false><<<640, 256, 0, stream>>>(
        x, Wl1, bl1, Wr1, br1, Wres, bres, xlb, xrb, resb, N);
    k_gat<<<gblocks, 256, 0, stream>>>(csr_off, csr_src, A_csr,
                                       xlb, xrb, resb, We1, att1, ab1, lng1, lnb1, hb, N, npw);

    // ---- block 2 ----
    k_tf_mfma<128, 16, 128, true><<<640, 256, 0, stream>>>(
        hb, Wl2, bl2, Wr2, br2, Wr2, br2, xlb, xrb, xrb, N);
    k_gat<<<gblocks, 256, 0, stream>>>(csr_off, csr_src, A_csr,
                                       xlb, xrb, hb, We2, att2, ab2, lng2, lnb2, resb, N, npw);

    // ---- fused pool + readout ----
    k_pool_read<<<G, 128, 0, stream>>>(resb, goff, Wd1, bd1, Wd2, bd2, (float*)d_out, G);
}

// Round 15
// 618.920 us; speedup vs baseline: 1.0424x; 1.0424x over previous
//
#include <hip/hip_runtime.h>

typedef unsigned short u16;
typedef unsigned int   u32;
typedef __attribute__((ext_vector_type(8))) short short8;
typedef __attribute__((ext_vector_type(4))) float float4v;
typedef __attribute__((ext_vector_type(2))) float float2v;

#define NODE_D   38
#define EDGE_D   13
#define D_OUT    128
#define NEG_SLOPE 0.2f
#define LN_EPS   1e-5f

__device__ __forceinline__ float bf2f(u16 v) { return __uint_as_float(((u32)v) << 16); }
__device__ __forceinline__ u16 f2bf(float f) {
    u32 u = __float_as_uint(f);
    u += 0x7fffu + ((u >> 16) & 1u);   // round-to-nearest-even
    return (u16)(u >> 16);
}

// ---------------- degree count ----------------
__global__ void k_deg(const int* __restrict__ dst, int E, int* __restrict__ deg) {
    int e = blockIdx.x * blockDim.x + threadIdx.x;
    if (e >= E) return;
    atomicAdd(deg + dst[e], 1);
}

// ---------------- graph offsets directly from sorted batch (no atomics, no scan) ----------------
__global__ void k_goff(const int* __restrict__ batch, int N, int G, int* __restrict__ goff) {
    int i = blockIdx.x * blockDim.x + threadIdx.x;
    if (i >= N) return;
    int b = batch[i];
    int prev = (i == 0) ? -1 : batch[i - 1];
    for (int g = prev + 1; g <= b; g++) goff[g] = i;
    if (i == N - 1)
        for (int g = b + 1; g <= G; g++) goff[g] = N;
}

// ---------------- multi-block exclusive scan (chunk = 1024), adds `addone` per elem ----------------
#define SCAN_CHUNK 1024
__global__ void k_scan1(const int* __restrict__ cnt, int N, int addone, int* __restrict__ bsum) {
    __shared__ int sh[256];
    int base = blockIdx.x * SCAN_CHUNK;
    int t = threadIdx.x;
    int s = 0;
#pragma unroll
    for (int i = 0; i < 4; i++) { int idx = base + t * 4 + i; if (idx < N) s += cnt[idx] + addone; }
    sh[t] = s; __syncthreads();
    for (int ofs = 128; ofs > 0; ofs >>= 1) {
        if (t < ofs) sh[t] += sh[t + ofs];
        __syncthreads();
    }
    if (t == 0) bsum[blockIdx.x] = sh[0];
}
// parallel block-sum scan (nb <= 256 fast path; serial fallback)
__global__ void k_scan2(const int* __restrict__ bsum, int nb, int* __restrict__ boff) {
    __shared__ int sh[256];
    int t = threadIdx.x;
    if (nb <= 256) {
        int v = (t < nb) ? bsum[t] : 0;
        sh[t] = v; __syncthreads();
        for (int ofs = 1; ofs < 256; ofs <<= 1) {
            int x = (t >= ofs) ? sh[t - ofs] : 0;
            __syncthreads();
            sh[t] += x;
            __syncthreads();
        }
        if (t < nb) boff[t] = sh[t] - v;       // exclusive
        if (t == nb - 1) boff[nb] = sh[t];     // total
    } else if (t == 0) {
        int run = 0;
        for (int i = 0; i < nb; i++) { boff[i] = run; run += bsum[i]; }
        boff[nb] = run;
    }
}
__global__ void k_scan3(const int* __restrict__ cnt, int N, int addone,
                        const int* __restrict__ boff, int nb, int* __restrict__ off) {
    __shared__ int wtot[4];
    int base = blockIdx.x * SCAN_CHUNK;
    int t = threadIdx.x;
    int lane = t & 63, w = t >> 6;
    int v[4]; int s = 0;
#pragma unroll
    for (int i = 0; i < 4; i++) { int idx = base + t * 4 + i; v[i] = (idx < N) ? cnt[idx] + addone : 0; s += v[i]; }
    int inc = s;
#pragma unroll
    for (int ofs = 1; ofs < 64; ofs <<= 1) {
        int x = __shfl_up(inc, ofs, 64);
        if (lane >= ofs) inc += x;
    }
    if (lane == 63) wtot[w] = inc;
    __syncthreads();
    int wofs = 0;
    for (int i = 0; i < w; i++) wofs += wtot[i];
    int run = boff[blockIdx.x] + wofs + (inc - s);
#pragma unroll
    for (int i = 0; i < 4; i++) {
        int idx = base + t * 4 + i;
        if (idx < N) off[idx] = run;
        run += v[i];
    }
    if (blockIdx.x == 0 && t == 0) off[N] = boff[nb];
}

// ---------------- CSR fill: scatter src AND the bf16 A-row (16-wide, padded) ----------------
__global__ void k_fill(const int* __restrict__ src, const int* __restrict__ dst,
                       const float* __restrict__ eattr, int E,
                       const int* __restrict__ csr_off, int* __restrict__ fill,
                       int* __restrict__ csr_src, u16* __restrict__ A) {
    int e = blockIdx.x * blockDim.x + threadIdx.x;
    if (e >= E) return;
    int d = dst[e];
    int pos = csr_off[d] + atomicAdd(fill + d, 1);
    csr_src[pos] = src[e];
    u16 row[16];
#pragma unroll
    for (int k = 0; k < EDGE_D; k++) row[k] = f2bf(eattr[(size_t)e * EDGE_D + k]);
#pragma unroll
    for (int k = EDGE_D; k < 16; k++) row[k] = 0;
    uint4* rp = (uint4*)(A + (size_t)pos * 16);
    rp[0] = (uint4){(u32)row[0] | ((u32)row[1] << 16), (u32)row[2] | ((u32)row[3] << 16),
                    (u32)row[4] | ((u32)row[5] << 16), (u32)row[6] | ((u32)row[7] << 16)};
    rp[1] = (uint4){(u32)row[8] | ((u32)row[9] << 16), (u32)row[10] | ((u32)row[11] << 16),
                    (u32)row[12] | ((u32)row[13] << 16), (u32)row[14] | ((u32)row[15] << 16)};
}

// ---------------- self rows: mean of node's (contiguous) real A rows; also self csr_src ----------------
__global__ void k_self(const int* __restrict__ csr_off, int N,
                       int* __restrict__ csr_src, u16* __restrict__ A) {
    int tid = blockIdx.x * blockDim.x + threadIdx.x;
    if (tid >= N * 16) return;
    int n = tid >> 4, k = tid & 15;
    int b = csr_off[n], e2 = csr_off[n + 1] - 1;   // e2 = self slot
    u16 v = 0;
    if (k < EDGE_D) {
        float s = 0.f;
        for (int j = b; j < e2; j++) s += bf2f(A[(size_t)j * 16 + k]);
        v = f2bf(s / fmaxf((float)(e2 - b), 1.f));
    }
    A[(size_t)e2 * 16 + k] = v;
    if (k == 0) csr_src[e2] = n;
}

// ---------------- MFMA multi-output transform ----------------
template <int KPAD, int CT, int KREAL, bool IN_BF16>
__global__ __launch_bounds__(256) void k_tf_mfma(
    const void* __restrict__ in_v,
    const float* __restrict__ W0, const float* __restrict__ b0,
    const float* __restrict__ W1, const float* __restrict__ b1,
    const float* __restrict__ W2, const float* __restrict__ b2,
    u16* __restrict__ o0, u16* __restrict__ o1, u16* __restrict__ o2,
    int N) {
    constexpr int RS = KPAD + 8;
    __shared__ u16 Bsw[CT * 16 * RS];
    __shared__ float bsh[CT * 16];
    const float* Ws[3] = {W0, W1, W2};
    const float* bs[3] = {b0, b1, b2};
    u16* outs[3] = {o0, o1, o2};
    int t = threadIdx.x;
    for (int i = t; i < CT * 16 * KPAD; i += 256) {
        int c = i / KPAD, k = i - c * KPAD;
        float v = (k < KREAL) ? Ws[c >> 7][(size_t)k * 128 + (c & 127)] : 0.f;
        Bsw[c * RS + k] = f2bf(v);
    }
    for (int i = t; i < CT * 16; i += 256) bsh[i] = bs[i >> 7][i & 127];
    __syncthreads();

    int wid = t >> 6, lane = t & 63;
    int quad = lane >> 4, m = lane & 15;

    for (int g0 = blockIdx.x * 64; g0 < N; g0 += gridDim.x * 64) {
        int na = g0 + wid * 16 + m;
        if (na > N - 1) na = N - 1;
        short8 a[KPAD / 32];
        if (IN_BF16) {
            const u16* in = (const u16*)in_v;
#pragma unroll
            for (int kc = 0; kc < KPAD / 32; kc++)
                a[kc] = *(const short8*)(in + (size_t)na * KPAD + kc * 32 + quad * 8);
        } else {
            const float* in = (const float*)in_v;
#pragma unroll
            for (int kc = 0; kc < KPAD / 32; kc++)
#pragma unroll
                for (int j = 0; j < 8; j++) {
                    int k = kc * 32 + quad * 8 + j;
                    float v = (k < KREAL) ? in[(size_t)na * KREAL + k] : 0.f;
                    a[kc][j] = (short)f2bf(v);
                }
        }
        float4v acc[CT];
#pragma unroll
        for (int ct = 0; ct < CT; ct++) acc[ct] = (float4v){0.f, 0.f, 0.f, 0.f};
#pragma unroll
        for (int ct = 0; ct < CT; ct++) {
#pragma unroll
            for (int kc = 0; kc < KPAD / 32; kc++) {
                short8 b = *(const short8*)(&Bsw[(ct * 16 + m) * RS + kc * 32 + quad * 8]);
                acc[ct] = __builtin_amdgcn_mfma_f32_16x16x32_bf16(a[kc], b, acc[ct], 0, 0, 0);
            }
        }
#pragma unroll
        for (int ct = 0; ct < CT; ct++) {
            int col = ct * 16 + m;
            u16* op = outs[col >> 7];
            int cc = col & 127;
            float bv = bsh[col];
#pragma unroll
            for (int r = 0; r < 4; r++) {
                int node = g0 + wid * 16 + quad * 4 + r;
                if (node < N) op[(size_t)node * 128 + cc] = f2bf(acc[ct][r] + bv);
            }
        }
    }
}

// ---------------- fused GATv2 block: multi-node waves, packed-f32 math, dual prefetch ----------------
// (round-13 version: depth-2 cross-node pipeline, VGPR ~40 — best measured)
__global__ __launch_bounds__(256) void k_gat(
    const int* __restrict__ csr_off, const int* __restrict__ csr_src,
    const u16* __restrict__ A_csr,
    const u16* __restrict__ xl, const u16* __restrict__ xr,
    const u16* __restrict__ res, const float* __restrict__ We,
    const float* __restrict__ att, const float* __restrict__ ab,
    const float* __restrict__ lng, const float* __restrict__ lnb,
    u16* __restrict__ hout, int N, int npw) {
    int t = threadIdx.x;
    int wid = t >> 6, lane = t & 63;
    int wave = blockIdx.x * 4 + wid;
    int n0 = wave * npw;
    if (n0 >= N) return;
    int n1 = n0 + npw; if (n1 > N) n1 = N;

    // ---- node-invariant preamble (once per wave) ----
    float2v we2[EDGE_D];
#pragma unroll
    for (int k = 0; k < EDGE_D; k++)
        we2[k] = (float2v){We[k * D_OUT + 2 * lane], We[k * D_OUT + 2 * lane + 1]};
    float a0 = att[2 * lane], a1 = att[2 * lane + 1];
    float abv0 = ab[2 * lane], abv1 = ab[2 * lane + 1];
    float lg0 = lng[2 * lane], lg1 = lng[2 * lane + 1];
    float lb0 = lnb[2 * lane], lb1 = lnb[2 * lane + 1];

    const u32* xl32 = (const u32*)xl;
    int wbeg = csr_off[n0];
    int wend = csr_off[n1];

    // dual prefetch: next xl row + next A row, named registers
    u32 xw = xl32[(size_t)csr_src[wbeg] * 64 + lane];
    const uint4* ap = (const uint4*)(A_csr + (size_t)wbeg * 16);
    uint4 aq0 = ap[0], aq1 = ap[1];

    int i = wbeg;
    for (int n = n0; n < n1; n++) {
        int end = csr_off[n + 1];
        u32 xrw = ((const u32*)xr)[(size_t)n * 64 + lane];
        float2v xr2 = (float2v){bf2f((u16)(xrw & 0xffff)), bf2f((u16)(xrw >> 16))};

        float ssum = 0.f;
        float2v acc2 = (float2v){0.f, 0.f};
        for (; i < end; i++) {
            u32 xwc = xw;
            uint4 q0 = aq0, q1 = aq1;
            if (i + 1 < wend) {
                xw = xl32[(size_t)csr_src[i + 1] * 64 + lane];
                const uint4* ap2 = (const uint4*)(A_csr + (size_t)(i + 1) * 16);
                aq0 = ap2[0]; aq1 = ap2[1];
            }
            u32 dw[8] = {q0.x, q0.y, q0.z, q0.w, q1.x, q1.y, q1.z, q1.w};
            float2v ee = (float2v){0.f, 0.f};
#pragma unroll
            for (int k = 0; k < EDGE_D; k++) {
                u32 d = dw[k >> 1];
                float av = bf2f((u16)((k & 1) ? (d >> 16) : (d & 0xffff)));
                ee += we2[k] * av;                      // v_pk_fma_f32
            }
            float2v xs = (float2v){bf2f((u16)(xwc & 0xffff)), bf2f((u16)(xwc >> 16))};
            float2v z = xs + xr2 + ee;
            float z0 = z[0], z1 = z[1];
            z0 = (z0 > 0.f) ? z0 : z0 * NEG_SLOPE;
            z1 = (z1 > 0.f) ? z1 : z1 * NEG_SLOPE;
            float p = z0 * a0 + z1 * a1;
            p += __shfl_xor(p, 1, 64);
            p += __shfl_xor(p, 2, 64);
            p += __shfl_xor(p, 4, 64);
            p += __shfl_xor(p, 8, 64);
            float wgt = __expf(p);          // no max-subtraction: logits are O(1)
            ssum += wgt;
            acc2 += xs * wgt;               // v_pk_fma_f32
        }

        float inv = 1.f / ssum;
        float o0 = acc2[0] * inv + abv0;
        float o1 = acc2[1] * inv + abv1;
        o0 = (o0 > 0.f) ? o0 : (__expf(o0) - 1.f);   // ELU
        o1 = (o1 > 0.f) ? o1 : (__expf(o1) - 1.f);
        u32 rw = ((const u32*)res)[(size_t)n * 64 + lane];
        o0 += bf2f((u16)(rw & 0xffff));
        o1 += bf2f((u16)(rw >> 16));
        float sm = o0 + o1;
#pragma unroll
        for (int mk = 1; mk < 64; mk <<= 1) sm += __shfl_xor(sm, mk, 64);
        float mu = sm * (1.f / 128.f);
        float d0 = o0 - mu, d1 = o1 - mu;
        float vv = d0 * d0 + d1 * d1;
#pragma unroll
        for (int mk = 1; mk < 64; mk <<= 1) vv += __shfl_xor(vv, mk, 64);
        float rs = rsqrtf(vv * (1.f / 128.f) + LN_EPS);
        float h0 = d0 * rs * lg0 + lb0;
        float h1 = d1 * rs * lg1 + lb1;
        ((u32*)hout)[(size_t)n * 64 + lane] = (u32)f2bf(h0) | ((u32)f2bf(h1) << 16);
    }
}

// ---------------- fused mean-pool + readout MLP: one block (2 waves) per graph ----------------
__global__ __launch_bounds__(128) void k_pool_read(
    const u16* __restrict__ h2, const int* __restrict__ goff,
    const float* __restrict__ Wd1, const float* __restrict__ bd1,
    const float* __restrict__ Wd2, const float* __restrict__ bd2,
    float* __restrict__ out, int G) {
    __shared__ float psh[128];
    __shared__ float rsh[2][64];
    int g = blockIdx.x;
    int c = threadIdx.x;
    int b = goff[g], e = goff[g + 1];
    float s = 0.f;
    for (int n = b; n < e; n++) s += bf2f(h2[(size_t)n * 128 + c]);
    psh[c] = s / fmaxf((float)(e - b), 1.f);
    __syncthreads();
    int j = c & 63, hw = c >> 6;
    float acc = (hw == 0) ? bd1[j] : 0.f;
    int k0 = hw * 64;
    for (int k = k0; k < k0 + 64; k++)
        acc += psh[k] * Wd1[k * 64 + j];
    rsh[hw][j] = acc;
    __syncthreads();
    if (c < 64) {
        float a = fmaxf(rsh[0][c] + rsh[1][c], 0.f);
        float v = a * Wd2[c];
#pragma unroll
        for (int mk = 1; mk < 64; mk <<= 1) v += __shfl_xor(v, mk, 64);
        if (c == 0) out[g] = v + bd2[0];
    }
}

extern "C" void kernel_launch(void* const* d_in, const int* in_sizes, int n_in,
                              void* d_out, int out_size, void* d_ws, size_t ws_size,
                              hipStream_t stream) {
    const float* x     = (const float*)d_in[0];
    const int*   eidx  = (const int*)d_in[1];
    const float* eattr = (const float*)d_in[2];
    const int*   batch = (const int*)d_in[3];
    const float* Wl1 = (const float*)d_in[4],  *bl1 = (const float*)d_in[5];
    const float* Wr1 = (const float*)d_in[6],  *br1 = (const float*)d_in[7];
    const float* We1 = (const float*)d_in[8],  *att1 = (const float*)d_in[9],  *ab1 = (const float*)d_in[10];
    const float* lng1 = (const float*)d_in[11], *lnb1 = (const float*)d_in[12];
    const float* Wres = (const float*)d_in[13], *bres = (const float*)d_in[14];
    const float* Wl2 = (const float*)d_in[15], *bl2 = (const float*)d_in[16];
    const float* Wr2 = (const float*)d_in[17], *br2 = (const float*)d_in[18];
    const float* We2 = (const float*)d_in[19], *att2 = (const float*)d_in[20], *ab2 = (const float*)d_in[21];
    const float* lng2 = (const float*)d_in[22], *lnb2 = (const float*)d_in[23];
    const float* Wd1 = (const float*)d_in[24], *bd1 = (const float*)d_in[25];
    const float* Wd2 = (const float*)d_in[26], *bd2 = (const float*)d_in[27];

    int N = in_sizes[0] / NODE_D;
    int E = in_sizes[1] / 2;
    int G = out_size;
    int EN = E + N;
    const int* src = eidx;
    const int* dst = eidx + E;

    char* w = (char*)d_ws;
    auto alloc = [&](size_t bytes) -> char* {
        char* p = w;
        w += (bytes + 255) & ~(size_t)255;
        return p;
    };
    int NB = (N + SCAN_CHUNK - 1) / SCAN_CHUNK;
    // ---- persistent buffers ----
    int*   csr_off  = (int*)alloc((size_t)(N + 1) * 4);
    int*   csr_src  = (int*)alloc((size_t)EN * 4);
    u16*   A_csr    = (u16*)alloc((size_t)(EN + 64) * 16 * 2);
    u16*   xlb      = (u16*)alloc((size_t)N * D_OUT * 2);
    u16*   xrb      = (u16*)alloc((size_t)N * D_OUT * 2);
    u16*   resb     = (u16*)alloc((size_t)N * D_OUT * 2);  // res1, then h2 output
    u16*   hb       = (u16*)alloc((size_t)N * D_OUT * 2);
    int*   goff     = (int*)alloc((size_t)(G + 1) * 4);
    // ---- scratch (deg/fill adjacent -> one memset) ----
    size_t szN = ((size_t)N * 4 + 255) & ~(size_t)255;
    char*  zp   = alloc(2 * szN);
    int*   deg  = (int*)zp;
    int*   fill = (int*)(zp + szN);
    int*   bsum = (int*)alloc((size_t)(NB + 1) * 4);
    int*   boff = (int*)alloc((size_t)(NB + 1) * 4);

    hipMemsetAsync(zp, 0, 2 * szN, stream);

    // ---- degree count ----
    k_deg<<<(E + 255) / 256, 256, 0, stream>>>(dst, E, deg);
    // ---- graph offsets directly from sorted batch ----
    k_goff<<<(N + 255) / 256, 256, 0, stream>>>(batch, N, G, goff);

    // ---- CSR with self-loops folded in; A rows written at scatter time ----
    k_scan1<<<NB, 256, 0, stream>>>(deg, N, 1, bsum);
    k_scan2<<<1, 256, 0, stream>>>(bsum, NB, boff);
    k_scan3<<<NB, 256, 0, stream>>>(deg, N, 1, boff, NB, csr_off);
    k_fill<<<(E + 255) / 256, 256, 0, stream>>>(src, dst, eattr, E, csr_off, fill, csr_src, A_csr);
    k_self<<<((size_t)N * 16 + 255) / 256, 256, 0, stream>>>(csr_off, N, csr_src, A_csr);

    // ---- k_gat launch geometry: npw=2 -> ~50000 waves ----
    int npw = 2;
    int gblocks = (N + npw * 4 - 1) / (npw * 4);

    // ---- block 1 ----
    k_tf_mfma<64, 24, NODE_D, false><<<640, 256, 0, stream>>>(
        x, Wl1, bl1, Wr1, br1, Wres, bres, xlb, xrb, resb, N);
    k_gat<<<gblocks, 256, 0, stream>>>(csr_off, csr_src, A_csr,
                                       xlb, xrb, resb, We1, att1, ab1, lng1, lnb1, hb, N, npw);

    // ---- block 2 ----
    k_tf_mfma<128, 16, 128, true><<<640, 256, 0, stream>>>(
        hb, Wl2, bl2, Wr2, br2, Wr2, br2, xlb, xrb, xrb, N);
    k_gat<<<gblocks, 256, 0, stream>>>(csr_off, csr_src, A_csr,
                                       xlb, xrb, hb, We2, att2, ab2, lng2, lnb2, resb, N, npw);

    // ---- fused pool + readout ----
    k_pool_read<<<G, 128, 0, stream>>>(resb, goff, Wd1, bd1, Wd2, bd2, (float*)d_out, G);
}

// Round 16
// 577.502 us; speedup vs baseline: 1.1171x; 1.0717x over previous
//
#include <hip/hip_runtime.h>

typedef unsigned short u16;
typedef unsigned int   u32;
typedef __attribute__((ext_vector_type(8))) short short8;
typedef __attribute__((ext_vector_type(4))) float float4v;
typedef __attribute__((ext_vector_type(2))) float float2v;

#define NODE_D   38
#define EDGE_D   13
#define D_OUT    128
#define NEG_SLOPE 0.2f
#define LN_EPS   1e-5f

__device__ __forceinline__ float bf2f(u16 v) { return __uint_as_float(((u32)v) << 16); }
__device__ __forceinline__ u16 f2bf(float f) {
    u32 u = __float_as_uint(f);
    u += 0x7fffu + ((u >> 16) & 1u);   // round-to-nearest-even
    return (u16)(u >> 16);
}

// ---------------- fused: degree count + graph offsets from sorted batch ----------------
__global__ void k_pre(const int* __restrict__ dst, int E, int* __restrict__ deg,
                      const int* __restrict__ batch, int N, int G, int* __restrict__ goff) {
    int i = blockIdx.x * blockDim.x + threadIdx.x;
    if (i < E) atomicAdd(deg + dst[i], 1);
    if (i < N) {
        int b = batch[i];
        int prev = (i == 0) ? -1 : batch[i - 1];
        for (int g = prev + 1; g <= b; g++) goff[g] = i;
        if (i == N - 1)
            for (int g = b + 1; g <= G; g++) goff[g] = N;
    }
}

// ---------------- multi-block exclusive scan (chunk = 1024), adds `addone` per elem ----------------
#define SCAN_CHUNK 1024
__global__ void k_scan1(const int* __restrict__ cnt, int N, int addone, int* __restrict__ bsum) {
    __shared__ int sh[256];
    int base = blockIdx.x * SCAN_CHUNK;
    int t = threadIdx.x;
    int s = 0;
#pragma unroll
    for (int i = 0; i < 4; i++) { int idx = base + t * 4 + i; if (idx < N) s += cnt[idx] + addone; }
    sh[t] = s; __syncthreads();
    for (int ofs = 128; ofs > 0; ofs >>= 1) {
        if (t < ofs) sh[t] += sh[t + ofs];
        __syncthreads();
    }
    if (t == 0) bsum[blockIdx.x] = sh[0];
}
// parallel block-sum scan (nb <= 256 fast path; serial fallback)
__global__ void k_scan2(const int* __restrict__ bsum, int nb, int* __restrict__ boff) {
    __shared__ int sh[256];
    int t = threadIdx.x;
    if (nb <= 256) {
        int v = (t < nb) ? bsum[t] : 0;
        sh[t] = v; __syncthreads();
        for (int ofs = 1; ofs < 256; ofs <<= 1) {
            int x = (t >= ofs) ? sh[t - ofs] : 0;
            __syncthreads();
            sh[t] += x;
            __syncthreads();
        }
        if (t < nb) boff[t] = sh[t] - v;       // exclusive
        if (t == nb - 1) boff[nb] = sh[t];     // total
    } else if (t == 0) {
        int run = 0;
        for (int i = 0; i < nb; i++) { boff[i] = run; run += bsum[i]; }
        boff[nb] = run;
    }
}
__global__ void k_scan3(const int* __restrict__ cnt, int N, int addone,
                        const int* __restrict__ boff, int nb, int* __restrict__ off) {
    __shared__ int wtot[4];
    int base = blockIdx.x * SCAN_CHUNK;
    int t = threadIdx.x;
    int lane = t & 63, w = t >> 6;
    int v[4]; int s = 0;
#pragma unroll
    for (int i = 0; i < 4; i++) { int idx = base + t * 4 + i; v[i] = (idx < N) ? cnt[idx] + addone : 0; s += v[i]; }
    int inc = s;
#pragma unroll
    for (int ofs = 1; ofs < 64; ofs <<= 1) {
        int x = __shfl_up(inc, ofs, 64);
        if (lane >= ofs) inc += x;
    }
    if (lane == 63) wtot[w] = inc;
    __syncthreads();
    int wofs = 0;
    for (int i = 0; i < w; i++) wofs += wtot[i];
    int run = boff[blockIdx.x] + wofs + (inc - s);
#pragma unroll
    for (int i = 0; i < 4; i++) {
        int idx = base + t * 4 + i;
        if (idx < N) off[idx] = run;
        run += v[i];
    }
    if (blockIdx.x == 0 && t == 0) off[N] = boff[nb];
}

// ---------------- CSR fill: scatter src AND the bf16 A-row (16-wide, padded) ----------------
__global__ void k_fill(const int* __restrict__ src, const int* __restrict__ dst,
                       const float* __restrict__ eattr, int E,
                       const int* __restrict__ csr_off, int* __restrict__ fill,
                       int* __restrict__ csr_src, u16* __restrict__ A) {
    int e = blockIdx.x * blockDim.x + threadIdx.x;
    if (e >= E) return;
    int d = dst[e];
    int pos = csr_off[d] + atomicAdd(fill + d, 1);
    csr_src[pos] = src[e];
    u16 row[16];
#pragma unroll
    for (int k = 0; k < EDGE_D; k++) row[k] = f2bf(eattr[(size_t)e * EDGE_D + k]);
#pragma unroll
    for (int k = EDGE_D; k < 16; k++) row[k] = 0;
    uint4* rp = (uint4*)(A + (size_t)pos * 16);
    rp[0] = (uint4){(u32)row[0] | ((u32)row[1] << 16), (u32)row[2] | ((u32)row[3] << 16),
                    (u32)row[4] | ((u32)row[5] << 16), (u32)row[6] | ((u32)row[7] << 16)};
    rp[1] = (uint4){(u32)row[8] | ((u32)row[9] << 16), (u32)row[10] | ((u32)row[11] << 16),
                    (u32)row[12] | ((u32)row[13] << 16), (u32)row[14] | ((u32)row[15] << 16)};
}

// ---------------- self rows: mean of node's (contiguous) real A rows; also self csr_src ----------------
__global__ void k_self(const int* __restrict__ csr_off, int N,
                       int* __restrict__ csr_src, u16* __restrict__ A) {
    int tid = blockIdx.x * blockDim.x + threadIdx.x;
    if (tid >= N * 16) return;
    int n = tid >> 4, k = tid & 15;
    int b = csr_off[n], e2 = csr_off[n + 1] - 1;   // e2 = self slot
    u16 v = 0;
    if (k < EDGE_D) {
        float s = 0.f;
        for (int j = b; j < e2; j++) s += bf2f(A[(size_t)j * 16 + k]);
        v = f2bf(s / fmaxf((float)(e2 - b), 1.f));
    }
    A[(size_t)e2 * 16 + k] = v;
    if (k == 0) csr_src[e2] = n;
}

// ---------------- MFMA multi-output transform ----------------
template <int KPAD, int CT, int KREAL, bool IN_BF16>
__global__ __launch_bounds__(256) void k_tf_mfma(
    const void* __restrict__ in_v,
    const float* __restrict__ W0, const float* __restrict__ b0,
    const float* __restrict__ W1, const float* __restrict__ b1,
    const float* __restrict__ W2, const float* __restrict__ b2,
    u16* __restrict__ o0, u16* __restrict__ o1, u16* __restrict__ o2,
    int N) {
    constexpr int RS = KPAD + 8;
    __shared__ u16 Bsw[CT * 16 * RS];
    __shared__ float bsh[CT * 16];
    const float* Ws[3] = {W0, W1, W2};
    const float* bs[3] = {b0, b1, b2};
    u16* outs[3] = {o0, o1, o2};
    int t = threadIdx.x;
    for (int i = t; i < CT * 16 * KPAD; i += 256) {
        int c = i / KPAD, k = i - c * KPAD;
        float v = (k < KREAL) ? Ws[c >> 7][(size_t)k * 128 + (c & 127)] : 0.f;
        Bsw[c * RS + k] = f2bf(v);
    }
    for (int i = t; i < CT * 16; i += 256) bsh[i] = bs[i >> 7][i & 127];
    __syncthreads();

    int wid = t >> 6, lane = t & 63;
    int quad = lane >> 4, m = lane & 15;

    for (int g0 = blockIdx.x * 64; g0 < N; g0 += gridDim.x * 64) {
        int na = g0 + wid * 16 + m;
        if (na > N - 1) na = N - 1;
        short8 a[KPAD / 32];
        if (IN_BF16) {
            const u16* in = (const u16*)in_v;
#pragma unroll
            for (int kc = 0; kc < KPAD / 32; kc++)
                a[kc] = *(const short8*)(in + (size_t)na * KPAD + kc * 32 + quad * 8);
        } else {
            const float* in = (const float*)in_v;
#pragma unroll
            for (int kc = 0; kc < KPAD / 32; kc++)
#pragma unroll
                for (int j = 0; j < 8; j++) {
                    int k = kc * 32 + quad * 8 + j;
                    float v = (k < KREAL) ? in[(size_t)na * KREAL + k] : 0.f;
                    a[kc][j] = (short)f2bf(v);
                }
        }
        float4v acc[CT];
#pragma unroll
        for (int ct = 0; ct < CT; ct++) acc[ct] = (float4v){0.f, 0.f, 0.f, 0.f};
#pragma unroll
        for (int ct = 0; ct < CT; ct++) {
#pragma unroll
            for (int kc = 0; kc < KPAD / 32; kc++) {
                short8 b = *(const short8*)(&Bsw[(ct * 16 + m) * RS + kc * 32 + quad * 8]);
                acc[ct] = __builtin_amdgcn_mfma_f32_16x16x32_bf16(a[kc], b, acc[ct], 0, 0, 0);
            }
        }
#pragma unroll
        for (int ct = 0; ct < CT; ct++) {
            int col = ct * 16 + m;
            u16* op = outs[col >> 7];
            int cc = col & 127;
            float bv = bsh[col];
#pragma unroll
            for (int r = 0; r < 4; r++) {
                int node = g0 + wid * 16 + quad * 4 + r;
                if (node < N) op[(size_t)node * 128 + cc] = f2bf(acc[ct][r] + bv);
            }
        }
    }
}

// ---------------- fused GATv2 block: multi-node waves, packed-f32 math, dual prefetch ----------------
// (round-13 structure, npw=4; branch-free clamped prefetch)
__global__ __launch_bounds__(256) void k_gat(
    const int* __restrict__ csr_off, const int* __restrict__ csr_src,
    const u16* __restrict__ A_csr,
    const u16* __restrict__ xl, const u16* __restrict__ xr,
    const u16* __restrict__ res, const float* __restrict__ We,
    const float* __restrict__ att, const float* __restrict__ ab,
    const float* __restrict__ lng, const float* __restrict__ lnb,
    u16* __restrict__ hout, int N, int npw) {
    int t = threadIdx.x;
    int wid = t >> 6, lane = t & 63;
    int wave = blockIdx.x * 4 + wid;
    int n0 = wave * npw;
    if (n0 >= N) return;
    int n1 = n0 + npw; if (n1 > N) n1 = N;

    // ---- node-invariant preamble (once per wave) ----
    float2v we2[EDGE_D];
#pragma unroll
    for (int k = 0; k < EDGE_D; k++)
        we2[k] = (float2v){We[k * D_OUT + 2 * lane], We[k * D_OUT + 2 * lane + 1]};
    float a0 = att[2 * lane], a1 = att[2 * lane + 1];
    float abv0 = ab[2 * lane], abv1 = ab[2 * lane + 1];
    float lg0 = lng[2 * lane], lg1 = lng[2 * lane + 1];
    float lb0 = lnb[2 * lane], lb1 = lnb[2 * lane + 1];

    const u32* xl32 = (const u32*)xl;
    int wbeg = csr_off[n0];
    int wend = csr_off[n1];
    int cl = wend - 1;

    // dual prefetch: next xl row + next A row, named registers
    u32 xw = xl32[(size_t)csr_src[wbeg] * 64 + lane];
    const uint4* ap = (const uint4*)(A_csr + (size_t)wbeg * 16);
    uint4 aq0 = ap[0], aq1 = ap[1];

    int i = wbeg;
    for (int n = n0; n < n1; n++) {
        int end = csr_off[n + 1];
        u32 xrw = ((const u32*)xr)[(size_t)n * 64 + lane];
        float2v xr2 = (float2v){bf2f((u16)(xrw & 0xffff)), bf2f((u16)(xrw >> 16))};

        float ssum = 0.f;
        float2v acc2 = (float2v){0.f, 0.f};
        for (; i < end; i++) {
            u32 xwc = xw;
            uint4 q0 = aq0, q1 = aq1;
            {
                int ip = (i + 1 < wend) ? i + 1 : cl;   // branch-free clamp, always in-bounds
                xw = xl32[(size_t)csr_src[ip] * 64 + lane];
                const uint4* ap2 = (const uint4*)(A_csr + (size_t)ip * 16);
                aq0 = ap2[0]; aq1 = ap2[1];
            }
            u32 dw[8] = {q0.x, q0.y, q0.z, q0.w, q1.x, q1.y, q1.z, q1.w};
            float2v ee = (float2v){0.f, 0.f};
#pragma unroll
            for (int k = 0; k < EDGE_D; k++) {
                u32 d = dw[k >> 1];
                float av = bf2f((u16)((k & 1) ? (d >> 16) : (d & 0xffff)));
                ee += we2[k] * av;                      // v_pk_fma_f32
            }
            float2v xs = (float2v){bf2f((u16)(xwc & 0xffff)), bf2f((u16)(xwc >> 16))};
            float2v z = xs + xr2 + ee;
            float z0 = z[0], z1 = z[1];
            z0 = (z0 > 0.f) ? z0 : z0 * NEG_SLOPE;
            z1 = (z1 > 0.f) ? z1 : z1 * NEG_SLOPE;
            float p = z0 * a0 + z1 * a1;
            p += __shfl_xor(p, 1, 64);
            p += __shfl_xor(p, 2, 64);
            p += __shfl_xor(p, 4, 64);
            p += __shfl_xor(p, 8, 64);
            float wgt = __expf(p);          // no max-subtraction: logits are O(1)
            ssum += wgt;
            acc2 += xs * wgt;               // v_pk_fma_f32
        }

        float inv = 1.f / ssum;
        float o0 = acc2[0] * inv + abv0;
        float o1 = acc2[1] * inv + abv1;
        o0 = (o0 > 0.f) ? o0 : (__expf(o0) - 1.f);   // ELU
        o1 = (o1 > 0.f) ? o1 : (__expf(o1) - 1.f);
        u32 rw = ((const u32*)res)[(size_t)n * 64 + lane];
        o0 += bf2f((u16)(rw & 0xffff));
        o1 += bf2f((u16)(rw >> 16));
        float sm = o0 + o1;
#pragma unroll
        for (int mk = 1; mk < 64; mk <<= 1) sm += __shfl_xor(sm, mk, 64);
        float mu = sm * (1.f / 128.f);
        float d0 = o0 - mu, d1 = o1 - mu;
        float vv = d0 * d0 + d1 * d1;
#pragma unroll
        for (int mk = 1; mk < 64; mk <<= 1) vv += __shfl_xor(vv, mk, 64);
        float rs = rsqrtf(vv * (1.f / 128.f) + LN_EPS);
        float h0 = d0 * rs * lg0 + lb0;
        float h1 = d1 * rs * lg1 + lb1;
        ((u32*)hout)[(size_t)n * 64 + lane] = (u32)f2bf(h0) | ((u32)f2bf(h1) << 16);
    }
}

// ---------------- fused mean-pool + readout MLP: one block (2 waves) per graph ----------------
__global__ __launch_bounds__(128) void k_pool_read(
    const u16* __restrict__ h2, const int* __restrict__ goff,
    const float* __restrict__ Wd1, const float* __restrict__ bd1,
    const float* __restrict__ Wd2, const float* __restrict__ bd2,
    float* __restrict__ out, int G) {
    __shared__ float psh[128];
    __shared__ float rsh[2][64];
    int g = blockIdx.x;
    int c = threadIdx.x;
    int b = goff[g], e = goff[g + 1];
    float s = 0.f;
    for (int n = b; n < e; n++) s += bf2f(h2[(size_t)n * 128 + c]);
    psh[c] = s / fmaxf((float)(e - b), 1.f);
    __syncthreads();
    int j = c & 63, hw = c >> 6;
    float acc = (hw == 0) ? bd1[j] : 0.f;
    int k0 = hw * 64;
    for (int k = k0; k < k0 + 64; k++)
        acc += psh[k] * Wd1[k * 64 + j];
    rsh[hw][j] = acc;
    __syncthreads();
    if (c < 64) {
        float a = fmaxf(rsh[0][c] + rsh[1][c], 0.f);
        float v = a * Wd2[c];
#pragma unroll
        for (int mk = 1; mk < 64; mk <<= 1) v += __shfl_xor(v, mk, 64);
        if (c == 0) out[g] = v + bd2[0];
    }
}

extern "C" void kernel_launch(void* const* d_in, const int* in_sizes, int n_in,
                              void* d_out, int out_size, void* d_ws, size_t ws_size,
                              hipStream_t stream) {
    const float* x     = (const float*)d_in[0];
    const int*   eidx  = (const int*)d_in[1];
    const float* eattr = (const float*)d_in[2];
    const int*   batch = (const int*)d_in[3];
    const float* Wl1 = (const float*)d_in[4],  *bl1 = (const float*)d_in[5];
    const float* Wr1 = (const float*)d_in[6],  *br1 = (const float*)d_in[7];
    const float* We1 = (const float*)d_in[8],  *att1 = (const float*)d_in[9],  *ab1 = (const float*)d_in[10];
    const float* lng1 = (const float*)d_in[11], *lnb1 = (const float*)d_in[12];
    const float* Wres = (const float*)d_in[13], *bres = (const float*)d_in[14];
    const float* Wl2 = (const float*)d_in[15], *bl2 = (const float*)d_in[16];
    const float* Wr2 = (const float*)d_in[17], *br2 = (const float*)d_in[18];
    const float* We2 = (const float*)d_in[19], *att2 = (const float*)d_in[20], *ab2 = (const float*)d_in[21];
    const float* lng2 = (const float*)d_in[22], *lnb2 = (const float*)d_in[23];
    const float* Wd1 = (const float*)d_in[24], *bd1 = (const float*)d_in[25];
    const float* Wd2 = (const float*)d_in[26], *bd2 = (const float*)d_in[27];

    int N = in_sizes[0] / NODE_D;
    int E = in_sizes[1] / 2;
    int G = out_size;
    int EN = E + N;
    const int* src = eidx;
    const int* dst = eidx + E;

    char* w = (char*)d_ws;
    auto alloc = [&](size_t bytes) -> char* {
        char* p = w;
        w += (bytes + 255) & ~(size_t)255;
        return p;
    };
    int NB = (N + SCAN_CHUNK - 1) / SCAN_CHUNK;
    // ---- persistent buffers ----
    int*   csr_off  = (int*)alloc((size_t)(N + 1) * 4);
    int*   csr_src  = (int*)alloc((size_t)EN * 4);
    u16*   A_csr    = (u16*)alloc((size_t)(EN + 64) * 16 * 2);
    u16*   xlb      = (u16*)alloc((size_t)N * D_OUT * 2);
    u16*   xrb      = (u16*)alloc((size_t)N * D_OUT * 2);
    u16*   resb     = (u16*)alloc((size_t)N * D_OUT * 2);  // res1, then h2 output
    u16*   hb       = (u16*)alloc((size_t)N * D_OUT * 2);
    int*   goff     = (int*)alloc((size_t)(G + 1) * 4);
    // ---- scratch (deg/fill adjacent -> one memset) ----
    size_t szN = ((size_t)N * 4 + 255) & ~(size_t)255;
    char*  zp   = alloc(2 * szN);
    int*   deg  = (int*)zp;
    int*   fill = (int*)(zp + szN);
    int*   bsum = (int*)alloc((size_t)(NB + 1) * 4);
    int*   boff = (int*)alloc((size_t)(NB + 1) * 4);

    hipMemsetAsync(zp, 0, 2 * szN, stream);

    // ---- degree count + graph offsets (fused) ----
    int mx = (E > N) ? E : N;
    k_pre<<<(mx + 255) / 256, 256, 0, stream>>>(dst, E, deg, batch, N, G, goff);

    // ---- CSR with self-loops folded in; A rows written at scatter time ----
    k_scan1<<<NB, 256, 0, stream>>>(deg, N, 1, bsum);
    k_scan2<<<1, 256, 0, stream>>>(bsum, NB, boff);
    k_scan3<<<NB, 256, 0, stream>>>(deg, N, 1, boff, NB, csr_off);
    k_fill<<<(E + 255) / 256, 256, 0, stream>>>(src, dst, eattr, E, csr_off, fill, csr_src, A_csr);
    k_self<<<((size_t)N * 16 + 255) / 256, 256, 0, stream>>>(csr_off, N, csr_src, A_csr);

    // ---- k_gat launch geometry: npw=4 -> 25000 waves (measured sweet spot) ----
    int npw = 4;
    int gblocks = (N + npw * 4 - 1) / (npw * 4);

    // ---- block 1 ----
    k_tf_mfma<64, 24, NODE_D, false><<<640, 256, 0, stream>>>(
        x, Wl1, bl1, Wr1, br1, Wres, bres, xlb, xrb, resb, N);
    k_gat<<<gblocks, 256, 0, stream>>>(csr_off, csr_src, A_csr,
                                       xlb, xrb, resb, We1, att1, ab1, lng1, lnb1, hb, N, npw);

    // ---- block 2 ----
    k_tf_mfma<128, 16, 128, true><<<640, 256, 0, stream>>>(
        hb, Wl2, bl2, Wr2, br2, Wr2, br2, xlb, xrb, xrb, N);
    k_gat<<<gblocks, 256, 0, stream>>>(csr_off, csr_src, A_csr,
                                       xlb, xrb, hb, We2, att2, ab2, lng2, lnb2, resb, N, npw);

    // ---- fused pool + readout ----
    k_pool_read<<<G, 128, 0, stream>>>(resb, goff, Wd1, bd1, Wd2, bd2, (float*)d_out, G);
}